// Round 5
// baseline (356.398 us; speedup 1.0000x reference)
//
#include <hip/hip_runtime.h>
#include <stdint.h>

// DVH global loss, MI355X — fused single kernel (R5).
// B=4 batches, N=2^21 voxels/batch, 500 bins over [0,75].
// loss = mean_{b,j} ( suffix_sum_{k>j}(hist_p[b]-hist_g[b])[k] / (maskcount_b+1e-6) )^2
// Difference histogram is exact in ints. Last-block-done pattern does the
// scan + MSE inline, eliminating the separate reduce dispatch.

#define NBINS 500
#define NHIST 501          // searchsorted index c in [0,500]; c>=1 for d>=0
#define BATCH 4
#define NPB (1 << 21)      // elements per batch
#define VPB (NPB / 4)      // float4 per batch
#define THREADS 512        // 8 waves/block
#define WAVES 8
#define BLOCKS_PER_BATCH 256
#define TOTAL_BLOCKS (BLOCKS_PER_BATCH * BATCH)
#define STRIDE (BLOCKS_PER_BATCH * THREADS)   // 131072 float4; VPB/STRIDE == 4

// workspace layout (int32):
//   hist_diff : [b*512 + i], i<501, b<4      (offset 0)
//   maskcount : [2048 + b]
//   done_ctr  : [2052]
#define MC_OFF 2048
#define DONE_OFF 2052
#define WS_INTS 2053

__device__ __forceinline__ int bin_of(float d) {
    // c = # of fp32 bins k*STEP that are <= d  (jnp.linspace(0,75,500),
    // searchsorted side='right'); d >= 0 guaranteed.
    const float STEP = 75.0f / 499.0f;
    const float INV  = 499.0f / 75.0f;
    int k = (int)(d * INV);
    if (k > 499) k = 499;
    if ((float)k * STEP > d) --k;
    else if (k < 499 && (float)(k + 1) * STEP <= d) ++k;
    if ((float)k * STEP > d) --k;   // safety second pass (k>=0 since bins[0]=0<=d)
    return k + 1;                   // in [1,500]
}

__device__ __forceinline__ int ws_load(const int* p) {
    return __hip_atomic_load(p, __ATOMIC_RELAXED, __HIP_MEMORY_SCOPE_AGENT);
}

__global__ __launch_bounds__(THREADS) void dvh_fused_kernel(
        const float4* __restrict__ dp, const float4* __restrict__ dg,
        const float4* __restrict__ dm, int* __restrict__ ws,
        float* __restrict__ out) {
    __shared__ int shd[WAVES * 512];   // per-wave private histograms, 16 KB
    __shared__ int slast;
    __shared__ int wtot[WAVES];
    __shared__ float facc[WAVES];
    const int b = blockIdx.y;
    const int t = threadIdx.x;
    const int lane = t & 63;
    const int w = t >> 6;
    const int wbase = w << 9;          // wave_id * 512

    #pragma unroll
    for (int i = 0; i < WAVES; ++i) shd[i * 512 + t] = 0;
    __syncthreads();

    // ---- histogram phase ----
    const size_t base = (size_t)b * VPB + (size_t)blockIdx.x * THREADS + t;
    float4 m0 = dm[base];              float4 m1 = dm[base + STRIDE];
    float4 m2 = dm[base + 2 * STRIDE]; float4 m3 = dm[base + 3 * STRIDE];
    float4 p0 = dp[base];              float4 p1 = dp[base + STRIDE];
    float4 p2 = dp[base + 2 * STRIDE]; float4 p3 = dp[base + 3 * STRIDE];
    float4 g0 = dg[base];              float4 g1 = dg[base + STRIDE];
    float4 g2 = dg[base + 2 * STRIDE]; float4 g3 = dg[base + 3 * STRIDE];

    unsigned int myc = 0;
#define DO(mm, pp, gg) \
    if (mm != 0.0f) { atomicAdd(&shd[wbase + bin_of(pp)], 1); \
                      atomicAdd(&shd[wbase + bin_of(gg)], -1); ++myc; }
    DO(m0.x, p0.x, g0.x) DO(m0.y, p0.y, g0.y) DO(m0.z, p0.z, g0.z) DO(m0.w, p0.w, g0.w)
    DO(m1.x, p1.x, g1.x) DO(m1.y, p1.y, g1.y) DO(m1.z, p1.z, g1.z) DO(m1.w, p1.w, g1.w)
    DO(m2.x, p2.x, g2.x) DO(m2.y, p2.y, g2.y) DO(m2.z, p2.z, g2.z) DO(m2.w, p2.w, g2.w)
    DO(m3.x, p3.x, g3.x) DO(m3.y, p3.y, g3.y) DO(m3.z, p3.z, g3.z) DO(m3.w, p3.w, g3.w)
#undef DO
    // wave-reduce myc (avoid 512 same-address LDS atomics)
    #pragma unroll
    for (int off = 32; off > 0; off >>= 1) myc += __shfl_down(myc, off, 64);
    __syncthreads();

    // ---- merge into global ws ----
    if (t < NHIST) {
        int v = 0;
        #pragma unroll
        for (int i = 0; i < WAVES; ++i) v += shd[i * 512 + t];
        if (v) atomicAdd(&ws[b * 512 + t], v);
    }
    if (lane == 0 && myc) atomicAdd(&ws[MC_OFF + b], (int)myc);

    // ---- completion protocol ----
    __threadfence();       // drain this thread's atomics to device scope
    __syncthreads();       // all threads' fences done
    if (t == 0) {
        int old = atomicAdd(&ws[DONE_OFF], 1);
        slast = (old == TOTAL_BLOCKS - 1) ? 1 : 0;
    }
    __syncthreads();
    if (!slast) return;

    // ---- last block: scan + MSE (512 threads) ----
    float acc = 0.0f;
    for (int bb = 0; bb < BATCH; ++bb) {
        int v = (t < NHIST) ? ws_load(&ws[bb * 512 + t]) : 0;
        // intra-wave inclusive scan (no barriers)
        #pragma unroll
        for (int off = 1; off < 64; off <<= 1) {
            int n = __shfl_up(v, off, 64);
            if (lane >= off) v += n;
        }
        if (lane == 63) wtot[w] = v;
        __syncthreads();
        int offset = 0, total = 0;
        #pragma unroll
        for (int i = 0; i < WAVES; ++i) {
            int x = wtot[i];
            total += x;
            if (i < w) offset += x;
        }
        const int prefix = v + offset;   // inclusive prefix over hist-diff[0..t]
        const float denom = (float)ws_load(&ws[MC_OFF + bb]) + 1e-6f;
        if (t < NBINS) {
            // count_ge[j] diff = sum_{k>=j+1} d[k] = total - incl_prefix[j]
            float diff = (float)(total - prefix) / denom;
            acc += diff * diff;
        }
        __syncthreads();   // before wtot reuse next batch
    }

    #pragma unroll
    for (int off = 32; off > 0; off >>= 1) acc += __shfl_down(acc, off, 64);
    if (lane == 0) facc[w] = acc;
    __syncthreads();
    if (t == 0) {
        float s = 0.0f;
        #pragma unroll
        for (int i = 0; i < WAVES; ++i) s += facc[i];
        out[0] = s * (1.0f / (BATCH * NBINS));
    }
}

extern "C" void kernel_launch(void* const* d_in, const int* in_sizes, int n_in,
                              void* d_out, int out_size, void* d_ws, size_t ws_size,
                              hipStream_t stream) {
    const float4* dp = (const float4*)d_in[0];   // d_pred
    const float4* dg = (const float4*)d_in[1];   // d_gt
    const float4* dm = (const float4*)d_in[2];   // mask
    int* ws = (int*)d_ws;

    hipMemsetAsync(d_ws, 0, WS_INTS * sizeof(int), stream);

    dim3 grid(BLOCKS_PER_BATCH, BATCH);
    dvh_fused_kernel<<<grid, dim3(THREADS), 0, stream>>>(dp, dg, dm, ws, (float*)d_out);
}

// Round 6
// 202.006 us; speedup vs baseline: 1.7643x; 1.7643x over previous
//
#include <hip/hip_runtime.h>
#include <stdint.h>

// DVH global loss, MI355X (R6 = R4 structure, interleaved load issue order).
// B=4 batches, N=2^21 voxels/batch, 500 bins over [0,75].
// loss = mean_{b,j} ( suffix_sum_{k>j}(hist_p[b]-hist_g[b])[k] / (maskcount_b+1e-6) )^2
// Difference histogram is exact in ints.
// R5 lesson: NO in-kernel device-scope fences (L2 writeback thrash) — keep the
// 3-dispatch chain; dispatch boundaries are the cheap barrier.

#define NBINS 500
#define NHIST 501          // searchsorted index c in [0,500]; c>=1 for d>=0
#define BATCH 4
#define NPB (1 << 21)      // elements per batch
#define VPB (NPB / 4)      // float4 per batch
#define THREADS 512        // 8 waves/block
#define WAVES 8
#define BLOCKS_PER_BATCH 256
#define STRIDE (BLOCKS_PER_BATCH * THREADS)   // 131072 float4; VPB/STRIDE == 4

// workspace layout (int32):
//   hist_diff : [b*512 + i], i<501, b<4      (offset 0)
//   maskcount : [2048 + b]
#define MC_OFF 2048
#define WS_INTS 2052

__device__ __forceinline__ int bin_of(float d) {
    // c = # of fp32 bins k*STEP that are <= d  (jnp.linspace(0,75,500),
    // searchsorted side='right'); d >= 0 guaranteed.
    const float STEP = 75.0f / 499.0f;
    const float INV  = 499.0f / 75.0f;
    int k = (int)(d * INV);
    if (k > 499) k = 499;
    if ((float)k * STEP > d) --k;
    else if (k < 499 && (float)(k + 1) * STEP <= d) ++k;
    if ((float)k * STEP > d) --k;   // safety second pass (k>=0 since bins[0]=0<=d)
    return k + 1;                   // in [1,500]
}

__global__ __launch_bounds__(THREADS) void dvh_hist_kernel(
        const float4* __restrict__ dp, const float4* __restrict__ dg,
        const float4* __restrict__ dm, int* __restrict__ ws) {
    __shared__ int shd[WAVES * 512];   // per-wave private histograms, 16 KB
    const int b = blockIdx.y;
    const int t = threadIdx.x;
    const int lane = t & 63;
    const int wbase = (t >> 6) << 9;   // wave_id * 512

    #pragma unroll
    for (int i = 0; i < WAVES; ++i) shd[i * 512 + t] = 0;
    __syncthreads();

    // Each thread owns 4 float4s per array. Issue loads INTERLEAVED per chunk
    // (m,p,g) so chunk-0 compute starts after 3 loads, overlapping the rest
    // (R3's grouped order exposed 9/12 of the load stream before any compute).
    const size_t base = (size_t)b * VPB + (size_t)blockIdx.x * THREADS + t;
    float4 m0 = dm[base];              float4 p0 = dp[base];              float4 g0 = dg[base];
    float4 m1 = dm[base + STRIDE];     float4 p1 = dp[base + STRIDE];     float4 g1 = dg[base + STRIDE];
    float4 m2 = dm[base + 2 * STRIDE]; float4 p2 = dp[base + 2 * STRIDE]; float4 g2 = dg[base + 2 * STRIDE];
    float4 m3 = dm[base + 3 * STRIDE]; float4 p3 = dp[base + 3 * STRIDE]; float4 g3 = dg[base + 3 * STRIDE];

    unsigned int myc = 0;
#define DO(mm, pp, gg) \
    if (mm != 0.0f) { atomicAdd(&shd[wbase + bin_of(pp)], 1); \
                      atomicAdd(&shd[wbase + bin_of(gg)], -1); ++myc; }
    DO(m0.x, p0.x, g0.x) DO(m0.y, p0.y, g0.y) DO(m0.z, p0.z, g0.z) DO(m0.w, p0.w, g0.w)
    DO(m1.x, p1.x, g1.x) DO(m1.y, p1.y, g1.y) DO(m1.z, p1.z, g1.z) DO(m1.w, p1.w, g1.w)
    DO(m2.x, p2.x, g2.x) DO(m2.y, p2.y, g2.y) DO(m2.z, p2.z, g2.z) DO(m2.w, p2.w, g2.w)
    DO(m3.x, p3.x, g3.x) DO(m3.y, p3.y, g3.y) DO(m3.z, p3.z, g3.z) DO(m3.w, p3.w, g3.w)
#undef DO
    // wave-reduce myc (one global atomic per wave, no same-address LDS storm)
    #pragma unroll
    for (int off = 32; off > 0; off >>= 1) myc += __shfl_down(myc, off, 64);
    __syncthreads();

    // Merge 8 wave-histograms -> global (conflict-free: lanes read consecutive bins)
    if (t < NHIST) {
        int v = 0;
        #pragma unroll
        for (int i = 0; i < WAVES; ++i) v += shd[i * 512 + t];
        if (v) atomicAdd(&ws[b * 512 + t], v);
    }
    if (lane == 0 && myc) atomicAdd(&ws[MC_OFF + b], (int)myc);
}

__global__ __launch_bounds__(512) void dvh_reduce_kernel(
        const int* __restrict__ ws, float* __restrict__ out) {
    __shared__ int wtot[8];
    __shared__ float facc[8];
    const int t = threadIdx.x;
    const int lane = t & 63;
    const int w = t >> 6;
    float acc = 0.0f;

    for (int b = 0; b < BATCH; ++b) {
        int v = (t < NHIST) ? ws[b * 512 + t] : 0;
        // intra-wave inclusive scan (no barriers)
        #pragma unroll
        for (int off = 1; off < 64; off <<= 1) {
            int n = __shfl_up(v, off, 64);
            if (lane >= off) v += n;
        }
        if (lane == 63) wtot[w] = v;
        __syncthreads();
        int offset = 0, total = 0;
        #pragma unroll
        for (int i = 0; i < 8; ++i) {
            int x = wtot[i];
            total += x;
            if (i < w) offset += x;
        }
        const int prefix = v + offset;   // inclusive prefix over hist-diff[0..t]
        const float denom = (float)ws[MC_OFF + b] + 1e-6f;
        if (t < NBINS) {
            // count_ge[j] diff = sum_{k>=j+1} d[k] = total - incl_prefix[j]
            float diff = (float)(total - prefix) / denom;
            acc += diff * diff;
        }
        __syncthreads();   // before wtot reuse next batch
    }

    // block reduction of acc
    #pragma unroll
    for (int off = 32; off > 0; off >>= 1) acc += __shfl_down(acc, off, 64);
    if (lane == 0) facc[w] = acc;
    __syncthreads();
    if (t == 0) {
        float s = 0.0f;
        #pragma unroll
        for (int i = 0; i < 8; ++i) s += facc[i];
        out[0] = s * (1.0f / (BATCH * NBINS));
    }
}

extern "C" void kernel_launch(void* const* d_in, const int* in_sizes, int n_in,
                              void* d_out, int out_size, void* d_ws, size_t ws_size,
                              hipStream_t stream) {
    const float4* dp = (const float4*)d_in[0];   // d_pred
    const float4* dg = (const float4*)d_in[1];   // d_gt
    const float4* dm = (const float4*)d_in[2];   // mask
    int* ws = (int*)d_ws;

    hipMemsetAsync(d_ws, 0, WS_INTS * sizeof(int), stream);

    dim3 grid(BLOCKS_PER_BATCH, BATCH);
    dvh_hist_kernel<<<grid, dim3(THREADS), 0, stream>>>(dp, dg, dm, ws);
    dvh_reduce_kernel<<<1, dim3(512), 0, stream>>>(ws, (float*)d_out);
}

// Round 7
// 126.271 us; speedup vs baseline: 2.8225x; 1.5998x over previous
//
#include <hip/hip_runtime.h>
#include <stdint.h>

// DVH global loss, MI355X (R7 = exact revert to R3, best measured: 126.06 us).
// B=4 batches, N=2^21 voxels/batch, 500 bins over [0,75].
// loss = mean_{b,j} ( suffix_sum_{k>j}(hist_p[b]-hist_g[b])[k] / (maskcount_b+1e-6) )^2
// Only the DIFFERENCE histogram matters: d[i] = hist_p[i] - hist_g[i] (exact in ints).
//
// Session lessons baked in:
//  - NO in-kernel device-scope fences (R5: L2 writeback thrash, 2.8x regression).
//  - Keep grouped-by-array load order (R6: interleaved order -> 3x worse schedule).
//  - Hist throughput is invariant to occupancy/ILP/LDS-privatization (R2/R3/R4):
//    the ~40us hist floor is harness reset writeback contention, not internal.

#define NBINS 500
#define NHIST 501          // searchsorted index c in [0,500]; c>=1 for d>=0
#define BATCH 4
#define NPB (1 << 21)      // elements per batch
#define VPB (NPB / 4)      // float4 per batch
#define THREADS 1024
#define BLOCKS_PER_BATCH 128
#define STRIDE (BLOCKS_PER_BATCH * THREADS)   // 131072 float4s; VPB/STRIDE == 4

// workspace layout (int32):
//   hist_diff : [b*512 + i], i<501, b<4      (offset 0)
//   maskcount : [2048 + b]
#define MC_OFF 2048
#define WS_INTS 2052

__device__ __forceinline__ int bin_of(float d) {
    // c = # of fp32 bins k*STEP that are <= d  (jnp.linspace(0,75,500),
    // searchsorted side='right'); d >= 0 guaranteed.
    const float STEP = 75.0f / 499.0f;
    const float INV  = 499.0f / 75.0f;
    int k = (int)(d * INV);
    if (k > 499) k = 499;
    if ((float)k * STEP > d) --k;
    else if (k < 499 && (float)(k + 1) * STEP <= d) ++k;
    if ((float)k * STEP > d) --k;   // safety second pass (k>=0 since bins[0]=0<=d)
    return k + 1;                   // in [1,500]
}

__global__ __launch_bounds__(THREADS) void dvh_hist_kernel(
        const float4* __restrict__ dp, const float4* __restrict__ dg,
        const float4* __restrict__ dm, int* __restrict__ ws) {
    __shared__ int shd[NHIST];
    __shared__ unsigned int smc;
    const int b = blockIdx.y;
    for (int i = threadIdx.x; i < NHIST; i += THREADS) shd[i] = 0;
    if (threadIdx.x == 0) smc = 0u;
    __syncthreads();

    // Each thread owns exactly 4 float4s per array, grouped-by-array issue order.
    const size_t base = (size_t)b * VPB + blockIdx.x * THREADS + threadIdx.x;
    float4 m0 = dm[base];              float4 m1 = dm[base + STRIDE];
    float4 m2 = dm[base + 2 * STRIDE]; float4 m3 = dm[base + 3 * STRIDE];
    float4 p0 = dp[base];              float4 p1 = dp[base + STRIDE];
    float4 p2 = dp[base + 2 * STRIDE]; float4 p3 = dp[base + 3 * STRIDE];
    float4 g0 = dg[base];              float4 g1 = dg[base + STRIDE];
    float4 g2 = dg[base + 2 * STRIDE]; float4 g3 = dg[base + 3 * STRIDE];

    unsigned int myc = 0;
#define DO(mm, pp, gg) \
    if (mm != 0.0f) { atomicAdd(&shd[bin_of(pp)], 1); atomicAdd(&shd[bin_of(gg)], -1); ++myc; }
    DO(m0.x, p0.x, g0.x) DO(m0.y, p0.y, g0.y) DO(m0.z, p0.z, g0.z) DO(m0.w, p0.w, g0.w)
    DO(m1.x, p1.x, g1.x) DO(m1.y, p1.y, g1.y) DO(m1.z, p1.z, g1.z) DO(m1.w, p1.w, g1.w)
    DO(m2.x, p2.x, g2.x) DO(m2.y, p2.y, g2.y) DO(m2.z, p2.z, g2.z) DO(m2.w, p2.w, g2.w)
    DO(m3.x, p3.x, g3.x) DO(m3.y, p3.y, g3.y) DO(m3.z, p3.z, g3.z) DO(m3.w, p3.w, g3.w)
#undef DO
    if (myc) atomicAdd(&smc, myc);
    __syncthreads();

    for (int i = threadIdx.x; i < NHIST; i += THREADS) {
        int v = shd[i];
        if (v) atomicAdd(&ws[b * 512 + i], v);
    }
    if (threadIdx.x == 0 && smc) atomicAdd((unsigned int*)&ws[MC_OFF + b], smc);
}

__global__ __launch_bounds__(512) void dvh_reduce_kernel(
        const int* __restrict__ ws, float* __restrict__ out) {
    __shared__ int wtot[8];
    __shared__ float facc[8];
    const int t = threadIdx.x;
    const int lane = t & 63;
    const int w = t >> 6;
    float acc = 0.0f;

    for (int b = 0; b < BATCH; ++b) {
        int v = (t < NHIST) ? ws[b * 512 + t] : 0;
        // intra-wave inclusive scan (no barriers)
        #pragma unroll
        for (int off = 1; off < 64; off <<= 1) {
            int n = __shfl_up(v, off, 64);
            if (lane >= off) v += n;
        }
        if (lane == 63) wtot[w] = v;
        __syncthreads();
        int offset = 0, total = 0;
        #pragma unroll
        for (int i = 0; i < 8; ++i) {
            int x = wtot[i];
            total += x;
            if (i < w) offset += x;
        }
        const int prefix = v + offset;   // inclusive prefix over hist-diff[0..t]
        const float denom = (float)((unsigned int)ws[MC_OFF + b]) + 1e-6f;
        if (t < NBINS) {
            // count_ge[j] diff = sum_{k>=j+1} d[k] = total - incl_prefix[j]
            float diff = (float)(total - prefix) / denom;
            acc += diff * diff;
        }
        __syncthreads();   // before wtot reuse next batch
    }

    // block reduction of acc
    #pragma unroll
    for (int off = 32; off > 0; off >>= 1) acc += __shfl_down(acc, off, 64);
    if (lane == 0) facc[w] = acc;
    __syncthreads();
    if (t == 0) {
        float s = 0.0f;
        #pragma unroll
        for (int i = 0; i < 8; ++i) s += facc[i];
        out[0] = s * (1.0f / (BATCH * NBINS));
    }
}

extern "C" void kernel_launch(void* const* d_in, const int* in_sizes, int n_in,
                              void* d_out, int out_size, void* d_ws, size_t ws_size,
                              hipStream_t stream) {
    const float4* dp = (const float4*)d_in[0];   // d_pred
    const float4* dg = (const float4*)d_in[1];   // d_gt
    const float4* dm = (const float4*)d_in[2];   // mask
    int* ws = (int*)d_ws;

    hipMemsetAsync(d_ws, 0, WS_INTS * sizeof(int), stream);

    dim3 grid(BLOCKS_PER_BATCH, BATCH);
    dvh_hist_kernel<<<grid, dim3(THREADS), 0, stream>>>(dp, dg, dm, ws);
    dvh_reduce_kernel<<<1, dim3(512), 0, stream>>>(ws, (float*)d_out);
}